// Round 1
// baseline (166.930 us; speedup 1.0000x reference)
//
#include <hip/hip_runtime.h>

#define NSEQ   2048
#define HEADS  16
#define DIM    64
#define BATCH  2
#define SCALE  0.125f      // 1/sqrt(64)

// Workspace: tree nodes with global index g in [NSEQ, 2*NSEQ-2) stored at
// slot (g - NSEQ), layout [b][slot][h][d]. 2048 slots reserved per array.
#define WSSLOTS 2048
#define WSELEMS ((size_t)BATCH * WSSLOTS * HEADS * DIM)

// offset of tree level j (j>=1) in the global node numbering; level 0 = leaves at 0.
__device__ __forceinline__ int level_offset(int j) {
    return (j == 0) ? 0 : (2 * NSEQ - ((2 * NSEQ) >> j));
}

__device__ __forceinline__ void reduce3(float& a, float& b, float& c) {
#pragma unroll
    for (int m = 1; m < 64; m <<= 1) {
        a += __shfl_xor(a, m, 64);
        b += __shfl_xor(b, m, 64);
        c += __shfl_xor(c, m, 64);
    }
}

// Parent = 3-way softmax mix of {mean, child0, child1} (reference semantics:
// fp32, max-subtracted exp, +1e-9 in denom). Lane = d. kc/vc returned per-lane.
__device__ __forceinline__ void make_parent(float k0, float k1, float v0, float v1,
                                            float& kc, float& vc) {
    float kp = 0.5f * (k0 + k1);
    float vp = 0.5f * (v0 + v1);
    float ss = kp * kp, sa = kp * k0, sb = kp * k1;
    reduce3(ss, sa, sb);
    ss *= SCALE; sa *= SCALE; sb *= SCALE;
    float mx = fmaxf(ss, fmaxf(sa, sb));
    float es = __expf(ss - mx), ea = __expf(sa - mx), eb = __expf(sb - mx);
    float inv = 1.0f / (es + ea + eb + 1e-9f);
    kc = (es * kp + ea * k0 + eb * k1) * inv;
    vc = (es * vp + ea * v0 + eb * v1) * inv;
}

// Kernel A: tree levels 1..7, one block per (b, h, 128-leaf chunk).
// 16 chunks per (b,h); each chunk produces 64+32+16+8+4+2+1 = 127 parents.
// Children ping-pong through LDS regions A=[0,64) (odd levels) / B=[64,96) (even).
__global__ __launch_bounds__(256) void tree_low(const float* __restrict__ K,
                                                const float* __restrict__ V,
                                                float* __restrict__ Kw,
                                                float* __restrict__ Vw) {
    __shared__ float Kb[96 * DIM];
    __shared__ float Vb[96 * DIM];
    int c  = blockIdx.x & 15;        // chunk
    int bh = blockIdx.x >> 4;
    int h  = bh & 15;
    int b  = bh >> 4;
    int wave = threadIdx.x >> 6;
    int d    = threadIdx.x & 63;

#pragma unroll
    for (int j = 1; j <= 7; ++j) {
        int P = 128 >> j;                      // parents this level within chunk
        int curOff  = (j & 1) ? 0 : 64;
        int prevOff = (j & 1) ? 64 : 0;
        for (int i = wave; i < P; i += 4) {
            float k0, k1, v0, v1;
            if (j == 1) {
                int n0 = c * 128 + 2 * i;
                int base = ((b * NSEQ + n0) * HEADS + h) * DIM + d;
                k0 = K[base]; k1 = K[base + HEADS * DIM];
                v0 = V[base]; v1 = V[base + HEADS * DIM];
            } else {
                int s = (prevOff + 2 * i) * DIM + d;
                k0 = Kb[s]; k1 = Kb[s + DIM];
                v0 = Vb[s]; v1 = Vb[s + DIM];
            }
            float kc, vc;
            make_parent(k0, k1, v0, v1, kc, vc);
            Kb[(curOff + i) * DIM + d] = kc;
            Vb[(curOff + i) * DIM + d] = vc;
            int g    = level_offset(j) + c * P + i;       // global node index
            int widx = ((b * WSSLOTS + (g - NSEQ)) * HEADS + h) * DIM + d;
            Kw[widx] = kc;
            Vw[widx] = vc;
        }
        __syncthreads();
    }
}

// Kernel B: tree levels 8..10, one block per (b,h). Children of level 8 are the
// 16 level-7 nodes written by tree_low (cross-kernel visibility via launch order).
__global__ __launch_bounds__(256) void tree_top(float* __restrict__ Kw,
                                                float* __restrict__ Vw) {
    __shared__ float Kb[12 * DIM];
    __shared__ float Vb[12 * DIM];
    int h = blockIdx.x & 15;
    int b = blockIdx.x >> 4;
    int wave = threadIdx.x >> 6;
    int d    = threadIdx.x & 63;

    // level 8: 8 parents; children g = 4064 + 2i (level 7); parent g = 4080 + i
    for (int i = wave; i < 8; i += 4) {
        int cbase = ((b * WSSLOTS + (level_offset(7) - NSEQ + 2 * i)) * HEADS + h) * DIM + d;
        float k0 = Kw[cbase], k1 = Kw[cbase + HEADS * DIM];
        float v0 = Vw[cbase], v1 = Vw[cbase + HEADS * DIM];
        float kc, vc;
        make_parent(k0, k1, v0, v1, kc, vc);
        Kb[i * DIM + d] = kc;  Vb[i * DIM + d] = vc;
        int widx = ((b * WSSLOTS + (level_offset(8) - NSEQ + i)) * HEADS + h) * DIM + d;
        Kw[widx] = kc;  Vw[widx] = vc;
    }
    __syncthreads();
    // level 9: 4 parents; children in LDS slots [0,8); stash parents at [8,12)
    {
        int i = wave;   // 4 waves, 4 parents
        int s = (2 * i) * DIM + d;
        float k0 = Kb[s], k1 = Kb[s + DIM];
        float v0 = Vb[s], v1 = Vb[s + DIM];
        float kc, vc;
        make_parent(k0, k1, v0, v1, kc, vc);
        __syncthreads();                 // done reading [0,8) before anyone writes? (writes go to [8,12) — safe; barrier keeps levels in lockstep)
        Kb[(8 + i) * DIM + d] = kc;  Vb[(8 + i) * DIM + d] = vc;
        int widx = ((b * WSSLOTS + (level_offset(9) - NSEQ + i)) * HEADS + h) * DIM + d;
        Kw[widx] = kc;  Vw[widx] = vc;
    }
    __syncthreads();
    // level 10: 2 parents; children in LDS slots [8,12); global store only
    if (wave < 2) {
        int i = wave;
        int s = (8 + 2 * i) * DIM + d;
        float k0 = Kb[s], k1 = Kb[s + DIM];
        float v0 = Vb[s], v1 = Vb[s + DIM];
        float kc, vc;
        make_parent(k0, k1, v0, v1, kc, vc);
        int widx = ((b * WSSLOTS + (level_offset(10) - NSEQ + i)) * HEADS + h) * DIM + d;
        Kw[widx] = kc;  Vw[widx] = vc;
    }
}

// Column l node index for query n: l=0 → self leaf; l>=1 → uncle at level l-1.
__device__ __forceinline__ int node_index(int n, int l) {
    if (l == 0) return n;
    int j = l - 1;
    int p = (n >> j) ^ 1;
    return level_offset(j) + p;
}

// Kernel C: attention. One wave per (b,n,h); lane = d.
__global__ __launch_bounds__(256) void attn(const float* __restrict__ Q,
                                            const float* __restrict__ K,
                                            const float* __restrict__ V,
                                            const float* __restrict__ Kw,
                                            const float* __restrict__ Vw,
                                            float* __restrict__ out) {
    int gw = blockIdx.x * 4 + (threadIdx.x >> 6);   // wave id over B*N*H
    int d  = threadIdx.x & 63;
    int h  = gw & 15;
    int n  = (gw >> 4) & (NSEQ - 1);
    int b  = gw >> 15;

    int qidx = ((b * NSEQ + n) * HEADS + h) * DIM + d;
    float q = Q[qidx];

    // column l active iff: l==0, or bit (l-1) of n set (uncle is in the past)
    unsigned active = 1u | (((unsigned)n & 0x7FFu) << 1);

    float prod[12];
#pragma unroll
    for (int l = 0; l < 12; ++l) {
        if (active & (1u << l)) {
            int g = node_index(n, l);
            const float* kp = (g < NSEQ)
                ? &K[((b * NSEQ + g) * HEADS + h) * DIM]
                : &Kw[((b * WSSLOTS + (g - NSEQ)) * HEADS + h) * DIM];
            prod[l] = q * kp[d];
        } else {
            prod[l] = 0.f;
        }
    }
    // 12 interleaved butterfly reductions (inactive columns reduce zeros)
#pragma unroll
    for (int m = 1; m < 64; m <<= 1) {
#pragma unroll
        for (int l = 0; l < 12; ++l)
            prod[l] += __shfl_xor(prod[l], m, 64);
    }

    float mx = -3.402823466e+38f;
#pragma unroll
    for (int l = 0; l < 12; ++l)
        if (active & (1u << l)) mx = fmaxf(mx, prod[l] * SCALE);

    float w[12];
    float sum = 0.f;
#pragma unroll
    for (int l = 0; l < 12; ++l) {
        float e = (active & (1u << l)) ? __expf(prod[l] * SCALE - mx) : 0.f;
        w[l] = e;
        sum += e;
    }
    float inv = 1.0f / sum;

    float o = 0.f;
#pragma unroll
    for (int l = 0; l < 12; ++l) {
        if (active & (1u << l)) {
            int g = node_index(n, l);
            const float* vp = (g < NSEQ)
                ? &V[((b * NSEQ + g) * HEADS + h) * DIM]
                : &Vw[((b * WSSLOTS + (g - NSEQ)) * HEADS + h) * DIM];
            o += w[l] * vp[d];
        }
    }
    out[qidx] = o * inv;
}

extern "C" void kernel_launch(void* const* d_in, const int* in_sizes, int n_in,
                              void* d_out, int out_size, void* d_ws, size_t ws_size,
                              hipStream_t stream) {
    const float* Q = (const float*)d_in[0];
    const float* K = (const float*)d_in[1];
    const float* V = (const float*)d_in[2];
    float* out = (float*)d_out;
    float* Kw = (float*)d_ws;              // needs 2 * 16 MiB of workspace
    float* Vw = Kw + WSELEMS;

    tree_low<<<BATCH * HEADS * 16, 256, 0, stream>>>(K, V, Kw, Vw);
    tree_top<<<BATCH * HEADS, 256, 0, stream>>>(Kw, Vw);
    attn<<<(BATCH * NSEQ * HEADS) / 4, 256, 0, stream>>>(Q, K, V, Kw, Vw, out);
}

// Round 2
// 129.304 us; speedup vs baseline: 1.2910x; 1.2910x over previous
//
#include <hip/hip_runtime.h>

#define NSEQ   2048
#define HEADS  16
#define DIM    64
#define BATCH  2
#define SCALE  0.125f      // 1/sqrt(64)

// Workspace: tree nodes with global index g in [NSEQ, 2*NSEQ-2) stored at
// slot (g - NSEQ), layout [b][slot][h][d]. 2048 slots reserved per array.
#define WSSLOTS 2048
#define WSELEMS ((size_t)BATCH * WSSLOTS * HEADS * DIM)
#define ROWF4   (DIM / 4)              // 16 float4 per row
#define HSTRIDE (HEADS * ROWF4)        // float4 stride between consecutive rows (n or slot)

__device__ __forceinline__ int level_offset(int j) {
    return (j == 0) ? 0 : (2 * NSEQ - ((2 * NSEQ) >> j));
}

__device__ __forceinline__ float dot4(float4 a, float4 b) {
    return a.x * b.x + a.y * b.y + a.z * b.z + a.w * b.w;
}

// Butterfly-sum 3 values across the 16-lane group (xor masks 1,2,4,8 stay in-group).
__device__ __forceinline__ void reduce3_16(float& a, float& b, float& c) {
#pragma unroll
    for (int m = 1; m < 16; m <<= 1) {
        a += __shfl_xor(a, m, 64);
        b += __shfl_xor(b, m, 64);
        c += __shfl_xor(c, m, 64);
    }
}

// Parent = 3-way softmax mix of {mean, child0, child1}; 16 lanes per parent,
// each lane owns 4 of the 64 dims (float4). Reference fp32 semantics.
__device__ __forceinline__ void make_parent4(float4 k0, float4 k1, float4 v0, float4 v1,
                                             float4& kc, float4& vc) {
    float4 kp, vp;
    kp.x = 0.5f * (k0.x + k1.x); kp.y = 0.5f * (k0.y + k1.y);
    kp.z = 0.5f * (k0.z + k1.z); kp.w = 0.5f * (k0.w + k1.w);
    vp.x = 0.5f * (v0.x + v1.x); vp.y = 0.5f * (v0.y + v1.y);
    vp.z = 0.5f * (v0.z + v1.z); vp.w = 0.5f * (v0.w + v1.w);
    float ss = dot4(kp, kp), sa = dot4(kp, k0), sb = dot4(kp, k1);
    reduce3_16(ss, sa, sb);
    ss *= SCALE; sa *= SCALE; sb *= SCALE;
    float mx = fmaxf(ss, fmaxf(sa, sb));
    float es = __expf(ss - mx), ea = __expf(sa - mx), eb = __expf(sb - mx);
    float inv = 1.0f / (es + ea + eb + 1e-9f);
    es *= inv; ea *= inv; eb *= inv;
    kc.x = es * kp.x + ea * k0.x + eb * k1.x;
    kc.y = es * kp.y + ea * k0.y + eb * k1.y;
    kc.z = es * kp.z + ea * k0.z + eb * k1.z;
    kc.w = es * kp.w + ea * k0.w + eb * k1.w;
    vc.x = es * vp.x + ea * v0.x + eb * v1.x;
    vc.y = es * vp.y + ea * v0.y + eb * v1.y;
    vc.z = es * vp.z + ea * v0.z + eb * v1.z;
    vc.w = es * vp.w + ea * v0.w + eb * v1.w;
}

// Kernel A: tree levels 1..7, one block per (b, h, 128-leaf chunk).
// 4 waves; each wave handles 4 parents at a time (16 lanes / parent, float4).
// Children ping-pong through LDS rows: odd levels write [0,64), even [64,96).
__global__ __launch_bounds__(256) void tree_low(const float* __restrict__ K,
                                                const float* __restrict__ V,
                                                float* __restrict__ Kw,
                                                float* __restrict__ Vw) {
    __shared__ float4 Kb[96 * ROWF4];
    __shared__ float4 Vb[96 * ROWF4];
    int c  = blockIdx.x & 15;
    int bh = blockIdx.x >> 4;
    int h  = bh & 15;
    int b  = bh >> 4;
    int wave = threadIdx.x >> 6;
    int lane = threadIdx.x & 63;
    int g = lane >> 4;                 // parent sub-index within wave
    int t = lane & 15;                 // float4 index within row

    const float4* K4 = (const float4*)K;
    const float4* V4 = (const float4*)V;
    float4* Kw4 = (float4*)Kw;
    float4* Vw4 = (float4*)Vw;

#pragma unroll
    for (int j = 1; j <= 7; ++j) {
        int P = 128 >> j;
        int curOff  = (j & 1) ? 0 : 64;
        int prevOff = (j & 1) ? 64 : 0;
        for (int i0 = 0; i0 < P; i0 += 16) {
            int p = i0 + wave * 4 + g;
            if (p < P) {
                float4 k0, k1, v0, v1;
                if (j == 1) {
                    int n0 = c * 128 + 2 * p;
                    const float4* Kr = K4 + ((size_t)(b * NSEQ + n0) * HEADS + h) * ROWF4;
                    const float4* Vr = V4 + ((size_t)(b * NSEQ + n0) * HEADS + h) * ROWF4;
                    k0 = Kr[t]; k1 = Kr[HSTRIDE + t];
                    v0 = Vr[t]; v1 = Vr[HSTRIDE + t];
                } else {
                    int s = (prevOff + 2 * p) * ROWF4 + t;
                    k0 = Kb[s]; k1 = Kb[s + ROWF4];
                    v0 = Vb[s]; v1 = Vb[s + ROWF4];
                }
                float4 kc, vc;
                make_parent4(k0, k1, v0, v1, kc, vc);
                Kb[(curOff + p) * ROWF4 + t] = kc;
                Vb[(curOff + p) * ROWF4 + t] = vc;
                int slot = level_offset(j) - NSEQ + c * P + p;
                size_t widx = ((size_t)(b * WSSLOTS + slot) * HEADS + h) * ROWF4 + t;
                Kw4[widx] = kc;
                Vw4[widx] = vc;
            }
        }
        __syncthreads();
    }
}

// Kernel B: tree levels 8..10, one block per (b,h).
__global__ __launch_bounds__(256) void tree_top(float* __restrict__ Kw,
                                                float* __restrict__ Vw) {
    __shared__ float4 Kb[12 * ROWF4];
    __shared__ float4 Vb[12 * ROWF4];
    int h = blockIdx.x & 15;
    int b = blockIdx.x >> 4;
    int wave = threadIdx.x >> 6;
    int lane = threadIdx.x & 63;
    int g = lane >> 4, t = lane & 15;
    int p = wave * 4 + g;

    float4* Kw4 = (float4*)Kw;
    float4* Vw4 = (float4*)Vw;

    // level 8: 8 parents; children = level-7 nodes (slots 2016+2p, 2016+2p+1)
    if (p < 8) {
        int cslot = level_offset(7) - NSEQ + 2 * p;
        size_t cb = ((size_t)(b * WSSLOTS + cslot) * HEADS + h) * ROWF4 + t;
        float4 k0 = Kw4[cb], k1 = Kw4[cb + HSTRIDE];
        float4 v0 = Vw4[cb], v1 = Vw4[cb + HSTRIDE];
        float4 kc, vc;
        make_parent4(k0, k1, v0, v1, kc, vc);
        Kb[p * ROWF4 + t] = kc;  Vb[p * ROWF4 + t] = vc;
        size_t widx = ((size_t)(b * WSSLOTS + level_offset(8) - NSEQ + p) * HEADS + h) * ROWF4 + t;
        Kw4[widx] = kc;  Vw4[widx] = vc;
    }
    __syncthreads();
    // level 9: 4 parents; children in LDS rows [0,8); parents stored rows [8,12)
    if (p < 4) {
        int s = (2 * p) * ROWF4 + t;
        float4 k0 = Kb[s], k1 = Kb[s + ROWF4];
        float4 v0 = Vb[s], v1 = Vb[s + ROWF4];
        float4 kc, vc;
        make_parent4(k0, k1, v0, v1, kc, vc);
        Kb[(8 + p) * ROWF4 + t] = kc;  Vb[(8 + p) * ROWF4 + t] = vc;
        size_t widx = ((size_t)(b * WSSLOTS + level_offset(9) - NSEQ + p) * HEADS + h) * ROWF4 + t;
        Kw4[widx] = kc;  Vw4[widx] = vc;
    }
    __syncthreads();
    // level 10: 2 parents; children in LDS rows [8,12)
    if (p < 2) {
        int s = (8 + 2 * p) * ROWF4 + t;
        float4 k0 = Kb[s], k1 = Kb[s + ROWF4];
        float4 v0 = Vb[s], v1 = Vb[s + ROWF4];
        float4 kc, vc;
        make_parent4(k0, k1, v0, v1, kc, vc);
        size_t widx = ((size_t)(b * WSSLOTS + level_offset(10) - NSEQ + p) * HEADS + h) * ROWF4 + t;
        Kw4[widx] = kc;  Vw4[widx] = vc;
    }
}

// Kernel C: attention. One wave = 4 heads (h0..h0+3) of the same (b,n):
// same node set for all 4 queries -> wave-uniform mask, and the 4 rows are
// contiguous -> each gather is one coalesced 1 KiB dwordx4 load per wave.
__global__ __launch_bounds__(256) void attn(const float* __restrict__ Q,
                                            const float* __restrict__ K,
                                            const float* __restrict__ V,
                                            const float* __restrict__ Kw,
                                            const float* __restrict__ Vw,
                                            float* __restrict__ out) {
    int w = blockIdx.x * 4 + (threadIdx.x >> 6);   // wave id over B*N*(H/4)
    int lane = threadIdx.x & 63;
    int g = lane >> 4;                             // head sub-index
    int t = lane & 15;                             // float4 index within row
    int h = (w & 3) * 4 + g;
    int n = (w >> 2) & (NSEQ - 1);
    int b = w >> 13;

    const float4* Q4 = (const float4*)Q;
    const float4* K4 = (const float4*)K;
    const float4* V4 = (const float4*)V;
    const float4* Kw4 = (const float4*)Kw;
    const float4* Vw4 = (const float4*)Vw;

    size_t qrow = ((size_t)(b * NSEQ + n) * HEADS + h) * ROWF4;
    float4 q4 = Q4[qrow + t];

    // column l active iff l==0 or bit (l-1) of n is set
    unsigned active = 1u | (((unsigned)n & 0x7FFu) << 1);

    float s[12];
#pragma unroll
    for (int l = 0; l < 12; ++l) {
        int gn;
        if (l == 0) gn = n;
        else { int j = l - 1; gn = level_offset(j) + ((n >> j) ^ 1); }
        const float4* kp = (gn < NSEQ)
            ? K4  + ((size_t)(b * NSEQ   +  gn)         * HEADS + h) * ROWF4
            : Kw4 + ((size_t)(b * WSSLOTS + (gn - NSEQ)) * HEADS + h) * ROWF4;
        s[l] = dot4(q4, kp[t]);
    }
#pragma unroll
    for (int m = 1; m < 16; m <<= 1) {
#pragma unroll
        for (int l = 0; l < 12; ++l)
            s[l] += __shfl_xor(s[l], m, 64);
    }

    float mx = -3.402823466e+38f;
#pragma unroll
    for (int l = 0; l < 12; ++l) {
        s[l] *= SCALE;
        if (active & (1u << l)) mx = fmaxf(mx, s[l]);
    }
    float sum = 0.f;
#pragma unroll
    for (int l = 0; l < 12; ++l) {
        float e = (active & (1u << l)) ? __expf(s[l] - mx) : 0.f;
        s[l] = e;
        sum += e;
    }
    float inv = 1.0f / sum;

    float4 o = make_float4(0.f, 0.f, 0.f, 0.f);
#pragma unroll
    for (int l = 0; l < 12; ++l) {
        int gn;
        if (l == 0) gn = n;
        else { int j = l - 1; gn = level_offset(j) + ((n >> j) ^ 1); }
        const float4* vp = (gn < NSEQ)
            ? V4  + ((size_t)(b * NSEQ   +  gn)         * HEADS + h) * ROWF4
            : Vw4 + ((size_t)(b * WSSLOTS + (gn - NSEQ)) * HEADS + h) * ROWF4;
        float4 v = vp[t];
        o.x += s[l] * v.x; o.y += s[l] * v.y;
        o.z += s[l] * v.z; o.w += s[l] * v.w;
    }
    float4* O4 = (float4*)out;
    O4[qrow + t] = make_float4(o.x * inv, o.y * inv, o.z * inv, o.w * inv);
}

extern "C" void kernel_launch(void* const* d_in, const int* in_sizes, int n_in,
                              void* d_out, int out_size, void* d_ws, size_t ws_size,
                              hipStream_t stream) {
    const float* Q = (const float*)d_in[0];
    const float* K = (const float*)d_in[1];
    const float* V = (const float*)d_in[2];
    float* out = (float*)d_out;
    float* Kw = (float*)d_ws;              // 16 MiB
    float* Vw = Kw + WSELEMS;              // 16 MiB

    tree_low<<<BATCH * HEADS * 16, 256, 0, stream>>>(K, V, Kw, Vw);
    tree_top<<<BATCH * HEADS, 256, 0, stream>>>(Kw, Vw);
    attn<<<(BATCH * NSEQ * HEADS / 4) / 4, 256, 0, stream>>>(Q, K, V, Kw, Vw, out);
}